// Round 10
// baseline (332.682 us; speedup 1.0000x reference)
//
#include <hip/hip_runtime.h>
#include <math.h>

#define N_PTS   131072
#define K_CONST 0.005f
#define D_U     0.001f
#define D_V     0.005f

typedef unsigned short u16;
typedef unsigned int   u32;
typedef __attribute__((ext_vector_type(8))) _Float16 f16x8;
typedef __attribute__((ext_vector_type(4))) float    f32x4;
typedef __attribute__((ext_vector_type(4))) u16      u16x4;
typedef __attribute__((ext_vector_type(8))) u16      u16x8;
typedef __attribute__((ext_vector_type(2))) u32      u32x2;
typedef __attribute__((ext_vector_type(4))) u32      u32x4;

__device__ __forceinline__ u16 f2h(float x){
    _Float16 h = (_Float16)x;
    return __builtin_bit_cast(u16, h);
}
__device__ __forceinline__ float h2f(u16 h){
    return (float)__builtin_bit_cast(_Float16, h);
}
__device__ __forceinline__ u32 pkrtz(float a, float b){
    return __builtin_bit_cast(u32, __builtin_amdgcn_cvt_pkrtz(a, b));
}
__device__ __forceinline__ u32x2 pk4(float a, float b, float c, float d){
    u32x2 r; r.x = pkrtz(a, b); r.y = pkrtz(c, d); return r;
}
__device__ __forceinline__ u32x4 pk8(const float* v){
    u32x4 r;
    r.x = pkrtz(v[0], v[1]); r.y = pkrtz(v[2], v[3]);
    r.z = pkrtz(v[4], v[5]); r.w = pkrtz(v[6], v[7]);
    return r;
}
__device__ __forceinline__ float tanh_fast(float z){
    float e = __expf(2.f * z);
    return 1.f - 2.f * __builtin_amdgcn_rcpf(e + 1.f);
}

// ---------------- prep: W1..W3 -> fp16, W^T fragment layout (ks-minor) ----------------
// store idx = (((L*16 + nt)*8 + ks)*64 + lane)*8 + j
// val = W[k][n], k = ks*32 + (lane>>4)*8 + j, n = nt*16 + (lane&15)
__global__ void prep_weights(const float* __restrict__ W1, const float* __restrict__ W2,
                             const float* __restrict__ W3, u16* __restrict__ ws)
{
    int gid  = blockIdx.x * 256 + threadIdx.x;   // 0 .. 24575
    int lane = gid & 63;
    int nt   = (gid >> 6) & 15;
    int ks   = (gid >> 10) & 7;
    int L    = gid >> 13;
    if (L >= 3) return;
    const float* W = (L == 0) ? W1 : ((L == 1) ? W2 : W3);
    int n  = nt * 16 + (lane & 15);
    int kg = lane >> 4;
    u16 h[8];
    #pragma unroll
    for (int j = 0; j < 8; ++j) {
        int k = ks * 32 + kg * 8 + j;
        h[j] = f2h(W[k * 256 + n]);
    }
    size_t ostore = ((size_t)((L * 16 + nt) * 8 + ks) * 64 + lane) * 8;
    *(u16x8*)&ws[ostore] = *(u16x8*)h;
}

// ---------------- main fused kernel: nt=4 + stream-split passes ----------------
// Block: 16 points, 4 waves (256 thr). Each wave owns 4 n-tiles (64 feats).
// 5 LDS planes [16 pts][256 feats] fp16, XOR swizzle byte = m*512 + ((2k)^((m&15)<<4)).
// planes: 0=v 1=t 2=x 3=y 4=lap.
// R9 post-mortem: LDS read BW was the wall (8-wave duplication: 154us > 124us MFMA
// floor). nt=4 halves H reads (77us). To still fit 4 waves/SIMD (128 regs), each
// layer runs as two stream-passes: pass1 {v,t} acc=32, pass2 {x,y,lap} acc=48;
// couple2 re-derives g = 1-a^2 from the fp16 a in the v-plane (feeds only the
// D_U/D_V-scaled streams, so the extra rounding is harmless).
// 4 blocks/CU (160KB LDS), 16 waves/CU.

#define K1STEP(KS, WC, WN, O)                                                                  \
  {                                                                                            \
    WN[0] = *(const f16x8*)(pL0 + (O));                                                        \
    WN[1] = *(const f16x8*)(pL1 + (O));                                                        \
    WN[2] = *(const f16x8*)(pL2 + (O));                                                        \
    WN[3] = *(const f16x8*)(pL3 + (O));                                                        \
    int hoff = mbase + ((64 * (KS) + 16 * kg) ^ mxor);                                         \
    f16x8 hv = *(const f16x8*)(Hb + 0 * 8192 + hoff);                                          \
    f16x8 ht = *(const f16x8*)(Hb + 1 * 8192 + hoff);                                          \
    __builtin_amdgcn_s_setprio(1);                                                             \
    _Pragma("unroll")                                                                          \
    for (int j = 0; j < 4; ++j) {                                                              \
      acc1[0][j] = __builtin_amdgcn_mfma_f32_16x16x32_f16(WC[j], hv, acc1[0][j], 0, 0, 0);     \
      acc1[1][j] = __builtin_amdgcn_mfma_f32_16x16x32_f16(WC[j], ht, acc1[1][j], 0, 0, 0);     \
    }                                                                                          \
    __builtin_amdgcn_s_setprio(0);                                                             \
  }

#define K1STEP7(WC)                                                                            \
  {                                                                                            \
    int hoff = mbase + ((64 * 7 + 16 * kg) ^ mxor);                                            \
    f16x8 hv = *(const f16x8*)(Hb + 0 * 8192 + hoff);                                          \
    f16x8 ht = *(const f16x8*)(Hb + 1 * 8192 + hoff);                                          \
    __builtin_amdgcn_s_setprio(1);                                                             \
    _Pragma("unroll")                                                                          \
    for (int j = 0; j < 4; ++j) {                                                              \
      acc1[0][j] = __builtin_amdgcn_mfma_f32_16x16x32_f16(WC[j], hv, acc1[0][j], 0, 0, 0);     \
      acc1[1][j] = __builtin_amdgcn_mfma_f32_16x16x32_f16(WC[j], ht, acc1[1][j], 0, 0, 0);     \
    }                                                                                          \
    __builtin_amdgcn_s_setprio(0);                                                             \
  }

#define K2STEP(KS, WC, WN, O)                                                                  \
  {                                                                                            \
    WN[0] = *(const f16x8*)(pL0 + (O));                                                        \
    WN[1] = *(const f16x8*)(pL1 + (O));                                                        \
    WN[2] = *(const f16x8*)(pL2 + (O));                                                        \
    WN[3] = *(const f16x8*)(pL3 + (O));                                                        \
    int hoff = mbase + ((64 * (KS) + 16 * kg) ^ mxor);                                         \
    f16x8 hx = *(const f16x8*)(Hb + 2 * 8192 + hoff);                                          \
    f16x8 hy = *(const f16x8*)(Hb + 3 * 8192 + hoff);                                          \
    f16x8 hl = *(const f16x8*)(Hb + 4 * 8192 + hoff);                                          \
    __builtin_amdgcn_s_setprio(1);                                                             \
    _Pragma("unroll")                                                                          \
    for (int j = 0; j < 4; ++j) {                                                              \
      acc2[0][j] = __builtin_amdgcn_mfma_f32_16x16x32_f16(WC[j], hx, acc2[0][j], 0, 0, 0);     \
      acc2[1][j] = __builtin_amdgcn_mfma_f32_16x16x32_f16(WC[j], hy, acc2[1][j], 0, 0, 0);     \
      acc2[2][j] = __builtin_amdgcn_mfma_f32_16x16x32_f16(WC[j], hl, acc2[2][j], 0, 0, 0);     \
    }                                                                                          \
    __builtin_amdgcn_s_setprio(0);                                                             \
  }

#define K2STEP7(WC)                                                                            \
  {                                                                                            \
    int hoff = mbase + ((64 * 7 + 16 * kg) ^ mxor);                                            \
    f16x8 hx = *(const f16x8*)(Hb + 2 * 8192 + hoff);                                          \
    f16x8 hy = *(const f16x8*)(Hb + 3 * 8192 + hoff);                                          \
    f16x8 hl = *(const f16x8*)(Hb + 4 * 8192 + hoff);                                          \
    __builtin_amdgcn_s_setprio(1);                                                             \
    _Pragma("unroll")                                                                          \
    for (int j = 0; j < 4; ++j) {                                                              \
      acc2[0][j] = __builtin_amdgcn_mfma_f32_16x16x32_f16(WC[j], hx, acc2[0][j], 0, 0, 0);     \
      acc2[1][j] = __builtin_amdgcn_mfma_f32_16x16x32_f16(WC[j], hy, acc2[1][j], 0, 0, 0);     \
      acc2[2][j] = __builtin_amdgcn_mfma_f32_16x16x32_f16(WC[j], hl, acc2[2][j], 0, 0, 0);     \
    }                                                                                          \
    __builtin_amdgcn_s_setprio(0);                                                             \
  }

__global__ __launch_bounds__(256, 4)
void pinn_mfma8(const float* __restrict__ t_in, const float* __restrict__ x_in,
                const float* __restrict__ y_in,
                const float* __restrict__ W0, const float* __restrict__ b0,
                const float* __restrict__ b1, const float* __restrict__ b2,
                const float* __restrict__ b3,
                const float* __restrict__ W4, const float* __restrict__ b4,
                const u16* __restrict__ ws,
                float* __restrict__ out)
{
    __shared__ u16 H[5 * 16 * 256];    // 40960 B
    char* Hb = (char*)H;

    const int tid  = threadIdx.x;
    const int lane = tid & 63;
    const int wv   = tid >> 6;         // wave 0..3

    // ---- layer 0: 3 -> 256 (16 thr/point, 16 feats each in 2 halves) ----
    {
        int p = tid & 15, c = tid >> 4;
        int g0 = blockIdx.x * 16 + p;
        float tv = t_in[g0], xv = x_in[g0], yv = y_in[g0];
        #pragma unroll
        for (int half = 0; half < 2; ++half) {
            int n0 = c * 16 + half * 8;
            float w0[8], w1[8], w2[8], bb[8];
            #pragma unroll
            for (int q = 0; q < 2; ++q) {
                *(float4*)&w0[q*4] = *(const float4*)&W0[0*256 + n0 + q*4];
                *(float4*)&w1[q*4] = *(const float4*)&W0[1*256 + n0 + q*4];
                *(float4*)&w2[q*4] = *(const float4*)&W0[2*256 + n0 + q*4];
                *(float4*)&bb[q*4] = *(const float4*)&b0[n0 + q*4];
            }
            float sv[8], st[8], sx[8], sy[8], sl[8];
            #pragma unroll
            for (int j = 0; j < 8; ++j) {
                float z = tv*w0[j] + xv*w1[j] + yv*w2[j] + bb[j];
                float a = tanh_fast(z);
                float g = 1.f - a*a;
                sv[j] = a;
                st[j] = g * w0[j];
                sx[j] = g * w1[j];
                sy[j] = g * w2[j];
                sl[j] = -2.f * a * g * (w1[j]*w1[j] + w2[j]*w2[j]);
            }
            int off = p * 512 + ((2 * n0) ^ (p << 4));
            *(u32x4*)(Hb + 0*8192 + off) = pk8(sv);
            *(u32x4*)(Hb + 1*8192 + off) = pk8(st);
            *(u32x4*)(Hb + 2*8192 + off) = pk8(sx);
            *(u32x4*)(Hb + 3*8192 + off) = pk8(sy);
            *(u32x4*)(Hb + 4*8192 + off) = pk8(sl);
        }
    }
    __syncthreads();

    const int mrow  = lane & 15;        // point (B-frag row / C col)
    const int kg    = lane >> 4;        // k-group / C row-group
    const int mxor  = mrow << 4;
    const int mbase = mrow * 512;

    // wave wv owns n-tiles {4wv .. 4wv+3}; nt stride 4096 u16, ks stride 512 (1KB imm),
    // L stride 65536 u16.
    const u16* pWb = ws + lane * 8;

    f16x8 whA[4], whB[4];

    #pragma unroll 1
    for (int L = 0; L < 3; ++L) {
        const float* bL = (L == 0) ? b1 : ((L == 1) ? b2 : b3);
        const u16* pL0 = pWb + L * 65536 + (wv * 4 + 0) * 4096;
        const u16* pL1 = pL0 + 4096;
        const u16* pL2 = pL0 + 8192;
        const u16* pL3 = pL0 + 12288;

        // ======== pass 1: streams {v, t} ========
        f32x4 acc1[2][4];
        #pragma unroll
        for (int s = 0; s < 2; ++s)
            #pragma unroll
            for (int j = 0; j < 4; ++j)
                acc1[s][j] = (f32x4){0.f, 0.f, 0.f, 0.f};

        #pragma unroll
        for (int j = 0; j < 4; ++j)
            whA[j] = *(const f16x8*)(pL0 + j * 4096);   // ks=0

        K1STEP(0, whA, whB, 1*512);
        K1STEP(1, whB, whA, 2*512);
        K1STEP(2, whA, whB, 3*512);
        K1STEP(3, whB, whA, 4*512);
        K1STEP(4, whA, whB, 5*512);
        K1STEP(5, whB, whA, 6*512);
        K1STEP(6, whA, whB, 7*512);
        K1STEP7(whB);

        __syncthreads();   // all v,t plane reads done (both passes of prev layer too)

        // ---- couple1: a = tanh(z0), write v,t planes ----
        #pragma unroll
        for (int nt = 0; nt < 4; ++nt) {
            int nb = (wv * 4 + nt) * 16 + kg * 4;
            float4 bv = *(const float4*)&bL[nb];
            float bva[4] = {bv.x, bv.y, bv.z, bv.w};
            float oa[4], ot[4];
            #pragma unroll
            for (int r = 0; r < 4; ++r) {
                float z0 = acc1[0][nt][r] + bva[r];
                float a  = tanh_fast(z0);
                float g  = 1.f - a * a;
                oa[r] = a;
                ot[r] = g * acc1[1][nt][r];
            }
            int off = mbase + ((2 * nb) ^ mxor);
            *(u32x2*)(Hb + 0*8192 + off) = pk4(oa[0], oa[1], oa[2], oa[3]);
            *(u32x2*)(Hb + 1*8192 + off) = pk4(ot[0], ot[1], ot[2], ot[3]);
        }
        // NOTE: no barrier — pass2 reads planes 2,3,4 (prev layer), couple1 wrote 0,1.

        // ======== pass 2: streams {x, y, lap} ========
        f32x4 acc2[3][4];
        #pragma unroll
        for (int s = 0; s < 3; ++s)
            #pragma unroll
            for (int j = 0; j < 4; ++j)
                acc2[s][j] = (f32x4){0.f, 0.f, 0.f, 0.f};

        #pragma unroll
        for (int j = 0; j < 4; ++j)
            whA[j] = *(const f16x8*)(pL0 + j * 4096);   // ks=0 again

        K2STEP(0, whA, whB, 1*512);
        K2STEP(1, whB, whA, 2*512);
        K2STEP(2, whA, whB, 3*512);
        K2STEP(3, whB, whA, 4*512);
        K2STEP(4, whA, whB, 5*512);
        K2STEP(5, whB, whA, 6*512);
        K2STEP(6, whA, whB, 7*512);
        K2STEP7(whB);

        __syncthreads();   // x,y,lap reads done; couple1's v-writes visible

        // ---- couple2: g from re-read a; write x,y,lap planes ----
        #pragma unroll
        for (int nt = 0; nt < 4; ++nt) {
            int nb = (wv * 4 + nt) * 16 + kg * 4;
            int off = mbase + ((2 * nb) ^ mxor);
            u16x4 av = *(const u16x4*)(Hb + 0*8192 + off);   // a (fp16, this layer)
            float ox[4], oy[4], ol[4];
            #pragma unroll
            for (int r = 0; r < 4; ++r) {
                float a  = h2f(av[r]);
                float g  = 1.f - a * a;
                float zx = acc2[0][nt][r];
                float zy = acc2[1][nt][r];
                float zl = acc2[2][nt][r];
                ox[r] = g * zx;
                oy[r] = g * zy;
                ol[r] = g * zl - 2.f * a * g * (zx*zx + zy*zy);
            }
            *(u32x2*)(Hb + 2*8192 + off) = pk4(ox[0], ox[1], ox[2], ox[3]);
            *(u32x2*)(Hb + 3*8192 + off) = pk4(oy[0], oy[1], oy[2], oy[3]);
            *(u32x2*)(Hb + 4*8192 + off) = pk4(ol[0], ol[1], ol[2], ol[3]);
        }
        __syncthreads();
    }

    // ---- final layer: 256 -> 2 (linear, fp32) + PDE residuals ----
    {
        int p = tid >> 4, i = tid & 15;
        float pu = 0.f, pv = 0.f, put = 0.f, pvt = 0.f, plu = 0.f, plv = 0.f;
        #pragma unroll
        for (int half = 0; half < 2; ++half) {
            int k0  = i * 16 + half * 8;
            int off = p * 512 + ((2 * k0) ^ (p << 4));
            u16x8 hv = *(const u16x8*)(Hb + 0*8192 + off);
            u16x8 ht = *(const u16x8*)(Hb + 1*8192 + off);
            u16x8 hl = *(const u16x8*)(Hb + 4*8192 + off);
            float w4[16];
            #pragma unroll
            for (int q = 0; q < 4; ++q)
                *(float4*)&w4[q*4] = *(const float4*)&W4[k0 * 2 + q * 4];
            #pragma unroll
            for (int j = 0; j < 8; ++j) {
                float vv = h2f(hv[j]);
                float tt = h2f(ht[j]);
                float ll = h2f(hl[j]);
                float wa = w4[2*j], wb2 = w4[2*j + 1];
                pu  += vv * wa;  pv  += vv * wb2;
                put += tt * wa;  pvt += tt * wb2;
                plu += ll * wa;  plv += ll * wb2;
            }
        }
        #pragma unroll
        for (int m = 1; m < 16; m <<= 1) {
            pu  += __shfl_xor(pu, m);   pv  += __shfl_xor(pv, m);
            put += __shfl_xor(put, m);  pvt += __shfl_xor(pvt, m);
            plu += __shfl_xor(plu, m);  plv += __shfl_xor(plv, m);
        }
        if (i == 0) {
            float u = pu + b4[0];
            float v = pv + b4[1];
            int gpt = blockIdx.x * 16 + p;
            float fo = u - u*u*u - K_CONST - v + D_U * plu - put;
            float go = u - v + D_V * plv - pvt;
            out[0 * N_PTS + gpt] = u;
            out[1 * N_PTS + gpt] = v;
            out[2 * N_PTS + gpt] = fo;
            out[3 * N_PTS + gpt] = go;
        }
    }
}

// ---------------- fallback (round-1 fp32 kernel) if ws too small ----------------
#define PTS   16
#define NTHR  256
#define HDIM  256
#define KC    32
#define HPAD  260

__global__ __launch_bounds__(NTHR, 1)
void pinn_diffreact_f32(const float* __restrict__ t_in, const float* __restrict__ x_in,
                        const float* __restrict__ y_in,
                        const float* __restrict__ W0, const float* __restrict__ b0,
                        const float* __restrict__ W1, const float* __restrict__ b1,
                        const float* __restrict__ W2, const float* __restrict__ b2,
                        const float* __restrict__ W3, const float* __restrict__ b3,
                        const float* __restrict__ W4, const float* __restrict__ b4,
                        float* __restrict__ out)
{
    __shared__ float Hs[6 * PTS * HPAD];
    __shared__ float Wc[KC * HDIM];
    const int tid = threadIdx.x;
    const int pt = tid >> 4;
    const int fbase = (tid & 15) * 4;
    const int gpt = blockIdx.x * PTS + pt;
    {
        const float tv = t_in[gpt], xv = x_in[gpt], yv = y_in[gpt];
        #pragma unroll
        for (int jv = 0; jv < 4; ++jv)
            #pragma unroll
            for (int q = 0; q < 4; ++q) {
                const int f = fbase + jv * 64 + q;
                const float w0 = W0[f], w1 = W0[256 + f], w2 = W0[512 + f];
                const float z = tv*w0 + xv*w1 + yv*w2 + b0[f];
                const float a = tanhf(z), g = 1.f - a*a;
                Hs[(0*PTS+pt)*HPAD+f] = a;
                Hs[(1*PTS+pt)*HPAD+f] = g*w0;
                Hs[(2*PTS+pt)*HPAD+f] = g*w1;
                Hs[(3*PTS+pt)*HPAD+f] = g*w2;
                Hs[(4*PTS+pt)*HPAD+f] = -2.f*a*g*w1*w1;
                Hs[(5*PTS+pt)*HPAD+f] = -2.f*a*g*w2*w2;
            }
    }
    __syncthreads();
    const float* Ws[3] = {W1, W2, W3};
    const float* bs[3] = {b1, b2, b3};
    for (int L = 0; L < 3; ++L) {
        const float* __restrict__ W = Ws[L];
        const float* __restrict__ b = bs[L];
        float acc[6][16];
        #pragma unroll
        for (int s = 0; s < 6; ++s)
            #pragma unroll
            for (int j = 0; j < 16; ++j) acc[s][j] = 0.f;
        for (int kc = 0; kc < HDIM / KC; ++kc) {
            __syncthreads();
            const float4* src = (const float4*)(W + kc * KC * HDIM);
            float4* dst = (float4*)Wc;
            #pragma unroll
            for (int i2 = 0; i2 < (KC * HDIM / 4) / NTHR; ++i2)
                dst[tid + i2 * NTHR] = src[tid + i2 * NTHR];
            __syncthreads();
            #pragma unroll
            for (int k4 = 0; k4 < KC; k4 += 4) {
                float4 h[6];
                #pragma unroll
                for (int s = 0; s < 6; ++s)
                    h[s] = *(const float4*)&Hs[(s*PTS+pt)*HPAD + kc*KC + k4];
                #pragma unroll
                for (int q = 0; q < 4; ++q) {
                    float hv[6];
                    #pragma unroll
                    for (int s = 0; s < 6; ++s)
                        hv[s] = (q==0) ? h[s].x : (q==1) ? h[s].y : (q==2) ? h[s].z : h[s].w;
                    #pragma unroll
                    for (int jv = 0; jv < 4; ++jv) {
                        const float4 wq = *(const float4*)&Wc[(k4+q)*HDIM + fbase + jv*64];
                        const float wvv[4] = {wq.x, wq.y, wq.z, wq.w};
                        #pragma unroll
                        for (int r = 0; r < 4; ++r)
                            #pragma unroll
                            for (int s = 0; s < 6; ++s)
                                acc[s][jv*4+r] += hv[s] * wvv[r];
                    }
                }
            }
        }
        __syncthreads();
        #pragma unroll
        for (int jv = 0; jv < 4; ++jv)
            #pragma unroll
            for (int q = 0; q < 4; ++q) {
                const int j = jv*4+q, f = fbase + jv*64 + q;
                const float z = acc[0][j] + b[f];
                const float a = tanhf(z), g = 1.f - a*a;
                const float zt = acc[1][j], zx = acc[2][j], zy = acc[3][j];
                const float zxx = acc[4][j], zyy = acc[5][j];
                Hs[(0*PTS+pt)*HPAD+f] = a;
                Hs[(1*PTS+pt)*HPAD+f] = g*zt;
                Hs[(2*PTS+pt)*HPAD+f] = g*zx;
                Hs[(3*PTS+pt)*HPAD+f] = g*zy;
                Hs[(4*PTS+pt)*HPAD+f] = g*zxx - 2.f*a*g*zx*zx;
                Hs[(5*PTS+pt)*HPAD+f] = g*zyy - 2.f*a*g*zy*zy;
            }
        __syncthreads();
    }
    float p[6][2];
    #pragma unroll
    for (int s = 0; s < 6; ++s) { p[s][0] = 0.f; p[s][1] = 0.f; }
    #pragma unroll
    for (int jv = 0; jv < 4; ++jv)
        #pragma unroll
        for (int q = 0; q < 4; ++q) {
            const int f = fbase + jv*64 + q;
            const float w0 = W4[f*2], w1 = W4[f*2+1];
            #pragma unroll
            for (int s = 0; s < 6; ++s) {
                const float hv = Hs[(s*PTS+pt)*HPAD+f];
                p[s][0] += hv*w0; p[s][1] += hv*w1;
            }
        }
    #pragma unroll
    for (int m = 1; m < 16; m <<= 1)
        #pragma unroll
        for (int s = 0; s < 6; ++s) {
            p[s][0] += __shfl_xor(p[s][0], m);
            p[s][1] += __shfl_xor(p[s][1], m);
        }
    if ((tid & 15) == 0) {
        const float u = p[0][0] + b4[0];
        const float v = p[0][1] + b4[1];
        const float ut = p[1][0], vt = p[1][1];
        const float uxx = p[4][0], vxx = p[4][1];
        const float uyy = p[5][0], vyy = p[5][1];
        const float fo = u - u*u*u - K_CONST - v + D_U*(uxx+uyy) - ut;
        const float go = u - v + D_V*(vxx+vyy) - vt;
        out[0*N_PTS+gpt] = u;
        out[1*N_PTS+gpt] = v;
        out[2*N_PTS+gpt] = fo;
        out[3*N_PTS+gpt] = go;
    }
}

extern "C" void kernel_launch(void* const* d_in, const int* in_sizes, int n_in,
                              void* d_out, int out_size, void* d_ws, size_t ws_size,
                              hipStream_t stream)
{
    const float* t_in = (const float*)d_in[0];
    const float* x_in = (const float*)d_in[1];
    const float* y_in = (const float*)d_in[2];
    const float* W0 = (const float*)d_in[3];
    const float* b0 = (const float*)d_in[4];
    const float* W1 = (const float*)d_in[5];
    const float* b1 = (const float*)d_in[6];
    const float* W2 = (const float*)d_in[7];
    const float* b2 = (const float*)d_in[8];
    const float* W3 = (const float*)d_in[9];
    const float* b3 = (const float*)d_in[10];
    const float* W4 = (const float*)d_in[11];
    const float* b4 = (const float*)d_in[12];
    float* out = (float*)d_out;

    const size_t WS_NEEDED = (size_t)3 * 8 * 16 * 64 * 8 * 2;  // 393216 B (fp16)
    if (ws_size >= WS_NEEDED) {
        u16* ws = (u16*)d_ws;
        hipLaunchKernelGGL(prep_weights, dim3(96), dim3(256), 0, stream, W1, W2, W3, ws);
        hipLaunchKernelGGL(pinn_mfma8, dim3(N_PTS / 16), dim3(256), 0, stream,
                           t_in, x_in, y_in, W0, b0, b1, b2, b3, W4, b4, ws, out);
    } else {
        hipLaunchKernelGGL(pinn_diffreact_f32, dim3(N_PTS / PTS), dim3(NTHR), 0, stream,
                           t_in, x_in, y_in, W0, b0, W1, b1, W2, b2, W3, b3, W4, b4, out);
    }
}

// Round 11
// 279.057 us; speedup vs baseline: 1.1922x; 1.1922x over previous
//
#include <hip/hip_runtime.h>
#include <math.h>

#define N_PTS   131072
#define K_CONST 0.005f
#define D_U     0.001f
#define D_V     0.005f

typedef unsigned short u16;
typedef unsigned int   u32;
typedef __attribute__((ext_vector_type(8)))  _Float16 f16x8;
typedef __attribute__((ext_vector_type(16))) float    f32x16;
typedef __attribute__((ext_vector_type(4)))  u16      u16x4;
typedef __attribute__((ext_vector_type(8)))  u16      u16x8;
typedef __attribute__((ext_vector_type(2)))  u32      u32x2;
typedef __attribute__((ext_vector_type(4)))  u32      u32x4;

__device__ __forceinline__ u16 f2h(float x){
    _Float16 h = (_Float16)x;
    return __builtin_bit_cast(u16, h);
}
__device__ __forceinline__ float h2f(u16 h){
    return (float)__builtin_bit_cast(_Float16, h);
}
__device__ __forceinline__ u32 pkrtz(float a, float b){
    return __builtin_bit_cast(u32, __builtin_amdgcn_cvt_pkrtz(a, b));
}
__device__ __forceinline__ u32x2 pk4(float a, float b, float c, float d){
    u32x2 r; r.x = pkrtz(a, b); r.y = pkrtz(c, d); return r;
}
__device__ __forceinline__ u32x4 pk8(const float* v){
    u32x4 r;
    r.x = pkrtz(v[0], v[1]); r.y = pkrtz(v[2], v[3]);
    r.z = pkrtz(v[4], v[5]); r.w = pkrtz(v[6], v[7]);
    return r;
}
__device__ __forceinline__ float tanh_fast(float z){
    float e = __expf(2.f * z);
    return 1.f - 2.f * __builtin_amdgcn_rcpf(e + 1.f);
}

// ---- prep: W1..W3 -> fp16, W^T fragment layout for 32x32x16 MFMA (ks-minor) ----
// store idx = (((L*8 + nt)*16 + ks)*64 + lane)*8 + j
// val = W[k][n], n = nt*32 + (lane&31), k = ks*16 + (lane>>5)*8 + j
__global__ void prep_weights32(const float* __restrict__ W1, const float* __restrict__ W2,
                               const float* __restrict__ W3, u16* __restrict__ ws)
{
    int gid  = blockIdx.x * 256 + threadIdx.x;   // 0 .. 24575
    int lane = gid & 63;
    int ks   = (gid >> 6) & 15;
    int nt   = (gid >> 10) & 7;
    int L    = gid >> 13;
    if (L >= 3) return;
    const float* W = (L == 0) ? W1 : ((L == 1) ? W2 : W3);
    int n  = nt * 32 + (lane & 31);
    int kg = lane >> 5;
    u16 h[8];
    #pragma unroll
    for (int j = 0; j < 8; ++j) {
        int k = ks * 16 + kg * 8 + j;
        h[j] = f2h(W[k * 256 + n]);
    }
    size_t ostore = ((size_t)((L * 8 + nt) * 16 + ks) * 64 + lane) * 8;
    *(u16x8*)&ws[ostore] = *(u16x8*)h;
}

// ---------------- main fused kernel: 32x32x16 MFMA ----------------
// Block: 32 points, 4 waves (256 thr). Each wave owns 2 n-tiles of 32 (64 feats).
// 5 LDS planes [32 pts][256 feats] fp16, plane stride 16384 B,
//   byte(plane,p,k) = plane*16384 + p*512 + ((2k) ^ ((p&15)<<4))
// planes: 0=v 1=t 2=x 3=y 4=lap.
// R10 post-mortem: 16x16x32 k-loop is LDS-issue-bound (5 b128 = 60cyc > 48cyc MFMA).
// 32x32x16: 4x FLOP per LDS byte -> per KSTEP 5 b128 (60cyc) vs 10 MFMA (320 SIMD-cyc);
// MFMA floor 124 -> ~103us. C layout (m74/m101): col=lane&31 (point),
// row=(reg&3)+8*(reg>>2)+4*(lane>>5) (n-in-tile) -> coupling fully lane-local.
// acc 5x2xf32x16=160 + ~70 arch < 256 regs at (256,2): 2 blocks/CU, LDS 2x80KB=160KB.

#define KSTEP(KS, WC, WN, P0, P1, O)                                                           \
  {                                                                                            \
    WN[0] = *(const f16x8*)((P0) + (O));                                                       \
    WN[1] = *(const f16x8*)((P1) + (O));                                                       \
    int hoff = mbase + ((32 * (KS) + kh16) ^ mxor);                                            \
    f16x8 hv = *(const f16x8*)(Hb + 0 * 16384 + hoff);                                         \
    f16x8 ht = *(const f16x8*)(Hb + 1 * 16384 + hoff);                                         \
    f16x8 hx = *(const f16x8*)(Hb + 2 * 16384 + hoff);                                         \
    f16x8 hy = *(const f16x8*)(Hb + 3 * 16384 + hoff);                                         \
    f16x8 hl = *(const f16x8*)(Hb + 4 * 16384 + hoff);                                         \
    __builtin_amdgcn_s_setprio(1);                                                             \
    _Pragma("unroll")                                                                          \
    for (int nt = 0; nt < 2; ++nt) {                                                           \
      acc[0][nt] = __builtin_amdgcn_mfma_f32_32x32x16_f16(WC[nt], hv, acc[0][nt], 0, 0, 0);    \
      acc[1][nt] = __builtin_amdgcn_mfma_f32_32x32x16_f16(WC[nt], ht, acc[1][nt], 0, 0, 0);    \
      acc[2][nt] = __builtin_amdgcn_mfma_f32_32x32x16_f16(WC[nt], hx, acc[2][nt], 0, 0, 0);    \
      acc[3][nt] = __builtin_amdgcn_mfma_f32_32x32x16_f16(WC[nt], hy, acc[3][nt], 0, 0, 0);    \
      acc[4][nt] = __builtin_amdgcn_mfma_f32_32x32x16_f16(WC[nt], hl, acc[4][nt], 0, 0, 0);    \
    }                                                                                          \
    __builtin_amdgcn_s_setprio(0);                                                             \
  }

__global__ __launch_bounds__(256, 2)
void pinn_mfma9(const float* __restrict__ t_in, const float* __restrict__ x_in,
                const float* __restrict__ y_in,
                const float* __restrict__ W0, const float* __restrict__ b0,
                const float* __restrict__ b1, const float* __restrict__ b2,
                const float* __restrict__ b3,
                const float* __restrict__ W4, const float* __restrict__ b4,
                const u16* __restrict__ ws,
                float* __restrict__ out)
{
    __shared__ u16 H[5 * 32 * 256];    // 81920 B
    char* Hb = (char*)H;

    const int tid  = threadIdx.x;
    const int lane = tid & 63;
    const int wv   = tid >> 6;         // wave 0..3

    // ---- layer 0: 3 -> 256 (8 thr/point, 32 feats each in 4 chunks) ----
    {
        int p = tid & 31, c = tid >> 5;      // c 0..7
        int g0 = blockIdx.x * 32 + p;
        float tv = t_in[g0], xv = x_in[g0], yv = y_in[g0];
        #pragma unroll
        for (int cc = 0; cc < 4; ++cc) {
            int n0 = c * 32 + cc * 8;
            float w0[8], w1[8], w2[8], bb[8];
            #pragma unroll
            for (int q = 0; q < 2; ++q) {
                *(float4*)&w0[q*4] = *(const float4*)&W0[0*256 + n0 + q*4];
                *(float4*)&w1[q*4] = *(const float4*)&W0[1*256 + n0 + q*4];
                *(float4*)&w2[q*4] = *(const float4*)&W0[2*256 + n0 + q*4];
                *(float4*)&bb[q*4] = *(const float4*)&b0[n0 + q*4];
            }
            float sv[8], st[8], sx[8], sy[8], sl[8];
            #pragma unroll
            for (int j = 0; j < 8; ++j) {
                float z = tv*w0[j] + xv*w1[j] + yv*w2[j] + bb[j];
                float a = tanh_fast(z);
                float g = 1.f - a*a;
                sv[j] = a;
                st[j] = g * w0[j];
                sx[j] = g * w1[j];
                sy[j] = g * w2[j];
                sl[j] = -2.f * a * g * (w1[j]*w1[j] + w2[j]*w2[j]);
            }
            int off = p * 512 + ((2 * n0) ^ ((p & 15) << 4));
            *(u32x4*)(Hb + 0*16384 + off) = pk8(sv);
            *(u32x4*)(Hb + 1*16384 + off) = pk8(st);
            *(u32x4*)(Hb + 2*16384 + off) = pk8(sx);
            *(u32x4*)(Hb + 3*16384 + off) = pk8(sy);
            *(u32x4*)(Hb + 4*16384 + off) = pk8(sl);
        }
    }
    __syncthreads();

    const int prow  = lane & 31;           // point (B-frag row / C col)
    const int kh16  = (lane >> 5) * 16;    // byte offset of k-half within 32-f16 k-step
    const int mxor  = (prow & 15) << 4;
    const int mbase = prow * 512;
    const int rbase = (lane >> 5) * 4;     // C row offset from lane-half

    // W fragment bases: wave wv owns n-tiles {2wv, 2wv+1}.
    // u16 strides: ks 512 (1KB imm-foldable), nt 8192, L 65536.
    const u16* pW0 = ws + (size_t)(wv * 2) * 8192 + lane * 8;
    const u16* pW1 = pW0 + 8192;

    f16x8 whA[2], whB[2];
    whA[0] = *(const f16x8*)(pW0);     // L=0, ks=0
    whA[1] = *(const f16x8*)(pW1);

    #pragma unroll 1
    for (int L = 0; L < 3; ++L) {
        const float* bL = (L == 0) ? b1 : ((L == 1) ? b2 : b3);

        f32x16 acc[5][2];
        #pragma unroll
        for (int s = 0; s < 5; ++s) {
            #pragma unroll
            for (int nt = 0; nt < 2; ++nt)
                #pragma unroll
                for (int r = 0; r < 16; ++r)
                    acc[s][nt][r] = 0.f;
        }

        const u16* pL0 = pW0 + L * 65536;
        const u16* pL1 = pW1 + L * 65536;
        const int  Ln  = (L < 2) ? (L + 1) : 2;
        const u16* pN0 = pW0 + Ln * 65536;
        const u16* pN1 = pW1 + Ln * 65536;

        KSTEP( 0, whA, whB, pL0, pL1,  1*512);
        KSTEP( 1, whB, whA, pL0, pL1,  2*512);
        KSTEP( 2, whA, whB, pL0, pL1,  3*512);
        KSTEP( 3, whB, whA, pL0, pL1,  4*512);
        KSTEP( 4, whA, whB, pL0, pL1,  5*512);
        KSTEP( 5, whB, whA, pL0, pL1,  6*512);
        KSTEP( 6, whA, whB, pL0, pL1,  7*512);
        KSTEP( 7, whB, whA, pL0, pL1,  8*512);
        KSTEP( 8, whA, whB, pL0, pL1,  9*512);
        KSTEP( 9, whB, whA, pL0, pL1, 10*512);
        KSTEP(10, whA, whB, pL0, pL1, 11*512);
        KSTEP(11, whB, whA, pL0, pL1, 12*512);
        KSTEP(12, whA, whB, pL0, pL1, 13*512);
        KSTEP(13, whB, whA, pL0, pL1, 14*512);
        KSTEP(14, whA, whB, pL0, pL1, 15*512);
        KSTEP(15, whB, whA, pN0, pN1, 0);      // prefetch next layer ks=0

        __syncthreads();   // all H reads of this layer done

        // ---- coupling + write next-layer H ----
        // lane holds C rows (reg&3)+8*(reg>>2)+rbase at col=point=prow.
        #pragma unroll
        for (int nt = 0; nt < 2; ++nt) {
            int ntb = (wv * 2 + nt) * 32;
            #pragma unroll
            for (int q = 0; q < 4; ++q) {
                int n0q = ntb + 8 * q + rbase;          // 4 consecutive n: regs 4q..4q+3
                float4 bv = *(const float4*)&bL[n0q];
                float bva[4] = {bv.x, bv.y, bv.z, bv.w};
                float oa[4], ot[4], ox[4], oy[4], ol[4];
                #pragma unroll
                for (int r = 0; r < 4; ++r) {
                    float z0 = acc[0][nt][4*q + r] + bva[r];
                    float a  = tanh_fast(z0);
                    float g  = 1.f - a * a;
                    float zt = acc[1][nt][4*q + r];
                    float zx = acc[2][nt][4*q + r];
                    float zy = acc[3][nt][4*q + r];
                    float zl = acc[4][nt][4*q + r];
                    oa[r] = a;
                    ot[r] = g * zt;
                    ox[r] = g * zx;
                    oy[r] = g * zy;
                    ol[r] = g * zl - 2.f * a * g * (zx*zx + zy*zy);
                }
                int off = mbase + ((2 * n0q) ^ mxor);
                *(u32x2*)(Hb + 0*16384 + off) = pk4(oa[0], oa[1], oa[2], oa[3]);
                *(u32x2*)(Hb + 1*16384 + off) = pk4(ot[0], ot[1], ot[2], ot[3]);
                *(u32x2*)(Hb + 2*16384 + off) = pk4(ox[0], ox[1], ox[2], ox[3]);
                *(u32x2*)(Hb + 3*16384 + off) = pk4(oy[0], oy[1], oy[2], oy[3]);
                *(u32x2*)(Hb + 4*16384 + off) = pk4(ol[0], ol[1], ol[2], ol[3]);
            }
        }
        __syncthreads();
    }

    // ---- final layer: 256 -> 2 (linear, fp32) + PDE residuals ----
    // p = tid>>3 (32 pts), i = tid&7 (8 thr/pt, 32 feats each in 4 chunks)
    {
        int p = tid >> 3, i = tid & 7;
        float pu = 0.f, pv = 0.f, put = 0.f, pvt = 0.f, plu = 0.f, plv = 0.f;
        #pragma unroll
        for (int cc = 0; cc < 4; ++cc) {
            int k0  = i * 32 + cc * 8;
            int off = p * 512 + ((2 * k0) ^ ((p & 15) << 4));
            u16x8 hv = *(const u16x8*)(Hb + 0*16384 + off);
            u16x8 ht = *(const u16x8*)(Hb + 1*16384 + off);
            u16x8 hl = *(const u16x8*)(Hb + 4*16384 + off);
            float w4[16];
            #pragma unroll
            for (int q = 0; q < 4; ++q)
                *(float4*)&w4[q*4] = *(const float4*)&W4[k0 * 2 + q * 4];
            #pragma unroll
            for (int j = 0; j < 8; ++j) {
                float vv = h2f(hv[j]);
                float tt = h2f(ht[j]);
                float ll = h2f(hl[j]);
                float wa = w4[2*j], wb2 = w4[2*j + 1];
                pu  += vv * wa;  pv  += vv * wb2;
                put += tt * wa;  pvt += tt * wb2;
                plu += ll * wa;  plv += ll * wb2;
            }
        }
        #pragma unroll
        for (int m = 1; m < 8; m <<= 1) {
            pu  += __shfl_xor(pu, m);   pv  += __shfl_xor(pv, m);
            put += __shfl_xor(put, m);  pvt += __shfl_xor(pvt, m);
            plu += __shfl_xor(plu, m);  plv += __shfl_xor(plv, m);
        }
        if (i == 0) {
            float u = pu + b4[0];
            float v = pv + b4[1];
            int gpt = blockIdx.x * 32 + p;
            float fo = u - u*u*u - K_CONST - v + D_U * plu - put;
            float go = u - v + D_V * plv - pvt;
            out[0 * N_PTS + gpt] = u;
            out[1 * N_PTS + gpt] = v;
            out[2 * N_PTS + gpt] = fo;
            out[3 * N_PTS + gpt] = go;
        }
    }
}

// ---------------- fallback (round-1 fp32 kernel) if ws too small ----------------
#define PTS   16
#define NTHR  256
#define HDIM  256
#define KC    32
#define HPAD  260

__global__ __launch_bounds__(NTHR, 1)
void pinn_diffreact_f32(const float* __restrict__ t_in, const float* __restrict__ x_in,
                        const float* __restrict__ y_in,
                        const float* __restrict__ W0, const float* __restrict__ b0,
                        const float* __restrict__ W1, const float* __restrict__ b1,
                        const float* __restrict__ W2, const float* __restrict__ b2,
                        const float* __restrict__ W3, const float* __restrict__ b3,
                        const float* __restrict__ W4, const float* __restrict__ b4,
                        float* __restrict__ out)
{
    __shared__ float Hs[6 * PTS * HPAD];
    __shared__ float Wc[KC * HDIM];
    const int tid = threadIdx.x;
    const int pt = tid >> 4;
    const int fbase = (tid & 15) * 4;
    const int gpt = blockIdx.x * PTS + pt;
    {
        const float tv = t_in[gpt], xv = x_in[gpt], yv = y_in[gpt];
        #pragma unroll
        for (int jv = 0; jv < 4; ++jv)
            #pragma unroll
            for (int q = 0; q < 4; ++q) {
                const int f = fbase + jv * 64 + q;
                const float w0 = W0[f], w1 = W0[256 + f], w2 = W0[512 + f];
                const float z = tv*w0 + xv*w1 + yv*w2 + b0[f];
                const float a = tanhf(z), g = 1.f - a*a;
                Hs[(0*PTS+pt)*HPAD+f] = a;
                Hs[(1*PTS+pt)*HPAD+f] = g*w0;
                Hs[(2*PTS+pt)*HPAD+f] = g*w1;
                Hs[(3*PTS+pt)*HPAD+f] = g*w2;
                Hs[(4*PTS+pt)*HPAD+f] = -2.f*a*g*w1*w1;
                Hs[(5*PTS+pt)*HPAD+f] = -2.f*a*g*w2*w2;
            }
    }
    __syncthreads();
    const float* Ws[3] = {W1, W2, W3};
    const float* bs[3] = {b1, b2, b3};
    for (int L = 0; L < 3; ++L) {
        const float* __restrict__ W = Ws[L];
        const float* __restrict__ b = bs[L];
        float acc[6][16];
        #pragma unroll
        for (int s = 0; s < 6; ++s)
            #pragma unroll
            for (int j = 0; j < 16; ++j) acc[s][j] = 0.f;
        for (int kc = 0; kc < HDIM / KC; ++kc) {
            __syncthreads();
            const float4* src = (const float4*)(W + kc * KC * HDIM);
            float4* dst = (float4*)Wc;
            #pragma unroll
            for (int i2 = 0; i2 < (KC * HDIM / 4) / NTHR; ++i2)
                dst[tid + i2 * NTHR] = src[tid + i2 * NTHR];
            __syncthreads();
            #pragma unroll
            for (int k4 = 0; k4 < KC; k4 += 4) {
                float4 h[6];
                #pragma unroll
                for (int s = 0; s < 6; ++s)
                    h[s] = *(const float4*)&Hs[(s*PTS+pt)*HPAD + kc*KC + k4];
                #pragma unroll
                for (int q = 0; q < 4; ++q) {
                    float hv[6];
                    #pragma unroll
                    for (int s = 0; s < 6; ++s)
                        hv[s] = (q==0) ? h[s].x : (q==1) ? h[s].y : (q==2) ? h[s].z : h[s].w;
                    #pragma unroll
                    for (int jv = 0; jv < 4; ++jv) {
                        const float4 wq = *(const float4*)&Wc[(k4+q)*HDIM + fbase + jv*64];
                        const float wvv[4] = {wq.x, wq.y, wq.z, wq.w};
                        #pragma unroll
                        for (int r = 0; r < 4; ++r)
                            #pragma unroll
                            for (int s = 0; s < 6; ++s)
                                acc[s][jv*4+r] += hv[s] * wvv[r];
                    }
                }
            }
        }
        __syncthreads();
        #pragma unroll
        for (int jv = 0; jv < 4; ++jv)
            #pragma unroll
            for (int q = 0; q < 4; ++q) {
                const int j = jv*4+q, f = fbase + jv*64 + q;
                const float z = acc[0][j] + b[f];
                const float a = tanhf(z), g = 1.f - a*a;
                const float zt = acc[1][j], zx = acc[2][j], zy = acc[3][j];
                const float zxx = acc[4][j], zyy = acc[5][j];
                Hs[(0*PTS+pt)*HPAD+f] = a;
                Hs[(1*PTS+pt)*HPAD+f] = g*zt;
                Hs[(2*PTS+pt)*HPAD+f] = g*zx;
                Hs[(3*PTS+pt)*HPAD+f] = g*zy;
                Hs[(4*PTS+pt)*HPAD+f] = g*zxx - 2.f*a*g*zx*zx;
                Hs[(5*PTS+pt)*HPAD+f] = g*zyy - 2.f*a*g*zy*zy;
            }
        __syncthreads();
    }
    float p[6][2];
    #pragma unroll
    for (int s = 0; s < 6; ++s) { p[s][0] = 0.f; p[s][1] = 0.f; }
    #pragma unroll
    for (int jv = 0; jv < 4; ++jv)
        #pragma unroll
        for (int q = 0; q < 4; ++q) {
            const int f = fbase + jv*64 + q;
            const float w0 = W4[f*2], w1 = W4[f*2+1];
            #pragma unroll
            for (int s = 0; s < 6; ++s) {
                const float hv = Hs[(s*PTS+pt)*HPAD+f];
                p[s][0] += hv*w0; p[s][1] += hv*w1;
            }
        }
    #pragma unroll
    for (int m = 1; m < 16; m <<= 1)
        #pragma unroll
        for (int s = 0; s < 6; ++s) {
            p[s][0] += __shfl_xor(p[s][0], m);
            p[s][1] += __shfl_xor(p[s][1], m);
        }
    if ((tid & 15) == 0) {
        const float u = p[0][0] + b4[0];
        const float v = p[0][1] + b4[1];
        const float ut = p[1][0], vt = p[1][1];
        const float uxx = p[4][0], vxx = p[4][1];
        const float uyy = p[5][0], vyy = p[5][1];
        const float fo = u - u*u*u - K_CONST - v + D_U*(uxx+uyy) - ut;
        const float go = u - v + D_V*(vxx+vyy) - vt;
        out[0*N_PTS+gpt] = u;
        out[1*N_PTS+gpt] = v;
        out[2*N_PTS+gpt] = fo;
        out[3*N_PTS+gpt] = go;
    }
}

extern "C" void kernel_launch(void* const* d_in, const int* in_sizes, int n_in,
                              void* d_out, int out_size, void* d_ws, size_t ws_size,
                              hipStream_t stream)
{
    const float* t_in = (const float*)d_in[0];
    const float* x_in = (const float*)d_in[1];
    const float* y_in = (const float*)d_in[2];
    const float* W0 = (const float*)d_in[3];
    const float* b0 = (const float*)d_in[4];
    const float* W1 = (const float*)d_in[5];
    const float* b1 = (const float*)d_in[6];
    const float* W2 = (const float*)d_in[7];
    const float* b2 = (const float*)d_in[8];
    const float* W3 = (const float*)d_in[9];
    const float* b3 = (const float*)d_in[10];
    const float* W4 = (const float*)d_in[11];
    const float* b4 = (const float*)d_in[12];
    float* out = (float*)d_out;

    const size_t WS_NEEDED = (size_t)3 * 65536 * 2;  // 393216 B (fp16 W frags)
    if (ws_size >= WS_NEEDED) {
        u16* ws = (u16*)d_ws;
        hipLaunchKernelGGL(prep_weights32, dim3(96), dim3(256), 0, stream, W1, W2, W3, ws);
        hipLaunchKernelGGL(pinn_mfma9, dim3(N_PTS / 32), dim3(256), 0, stream,
                           t_in, x_in, y_in, W0, b0, b1, b2, b3, W4, b4, ws, out);
    } else {
        hipLaunchKernelGGL(pinn_diffreact_f32, dim3(N_PTS / PTS), dim3(NTHR), 0, stream,
                           t_in, x_in, y_in, W0, b0, W1, b1, W2, b2, W3, b3, W4, b4, out);
    }
}